// Round 2
// baseline (1609.685 us; speedup 1.0000x reference)
//
#include <hip/hip_runtime.h>
#include <hip/hip_bf16.h>
#include <cstdint>
#include <cstddef>

#define BB 4
#define NN 4096
#define EE 65536
#define HID 128
#define FN 32
#define FE 16
#define NROUNDS 3

// h lives inside d_out: node n of batch b at out[(b*(NN+1) + 1 + n)*HID + j].
__device__ __forceinline__ size_t hrow(int b, int n) {
    return ((size_t)b * (NN + 1) + 1 + n) * HID;
}

__device__ __forceinline__ float silu(float x) {
    return x / (1.0f + expf(-x));
}

// ---------------- h0 = nodes @ W_node  (B*N rows, K=32, 128 cols) ----------
__global__ void proj_nodes_kernel(const float* __restrict__ nodes,
                                  const float* __restrict__ Wn,
                                  float* __restrict__ hbuf) {
    __shared__ float nd[8][FN];
    int t = threadIdx.x;              // col j in [0,128)
    int row0 = blockIdx.x * 8;        // global node row (b*NN + n)
    for (int i = 0; i < 2; ++i) {
        int idx = i * 128 + t; int r = idx >> 5; int c = idx & 31;
        nd[r][c] = nodes[(size_t)(row0 + r) * FN + c];
    }
    __syncthreads();
    float acc[8] = {0.f,0.f,0.f,0.f,0.f,0.f,0.f,0.f};
    #pragma unroll
    for (int k = 0; k < FN; ++k) {
        float w = Wn[k * HID + t];
        #pragma unroll
        for (int r = 0; r < 8; ++r) acc[r] += nd[r][k] * w;
    }
    #pragma unroll
    for (int r = 0; r < 8; ++r) {
        int row = row0 + r; int b = row >> 12; int n = row & (NN - 1);
        hbuf[hrow(b, n) + t] = acc[r];
    }
}

// ---- Wec[r] = W_edge (16x128) @ eW1[r][256:384] (128x128) -> (16x128) -----
__global__ void fuse_wec_kernel(const float* __restrict__ We,
                                const float* __restrict__ eW1,
                                float* __restrict__ Wec) {
    int t = threadIdx.x;              // col j
    int i = blockIdx.x & 15;          // raw edge-feat index
    int r = blockIdx.x >> 4;          // round
    const float* w1 = eW1 + ((size_t)r * 384 + 256) * HID;
    float acc = 0.f;
    for (int k = 0; k < HID; ++k)
        acc += We[i * HID + k] * w1[k * HID + t];
    Wec[((size_t)r * 16 + i) * HID + t] = acc;
}

// ---------------- marker rows of the output --------------------------------
__global__ void marker_kernel(const float* __restrict__ marker,
                              float* __restrict__ out) {
    int t = threadIdx.x;              // 512 threads: b = t>>7, j = t&127
    int b = t >> 7; int j = t & 127;
    out[((size_t)b * (NN + 1)) * HID + j] = marker[j];
}

// ------------- edge MLP + scatter-add.  16 edges / block, 256 thr ----------
__global__ __launch_bounds__(256)
void edge_kernel(const float* __restrict__ hbuf,
                 const float* __restrict__ edge_feat,
                 const int* __restrict__ edges,    // int32 pairs
                 const int* __restrict__ emask,
                 const float* __restrict__ W1,   // eW1[r], rows 0..255 used
                 const float* __restrict__ Wec,  // (16,128) folded ef weights
                 const float* __restrict__ b1,
                 const float* __restrict__ W2,
                 const float* __restrict__ b2,
                 float* __restrict__ agg) {
    __shared__ float xs[272][20];   // transposed: xs[k][edge], pad->16B rows
    __shared__ float ts[HID][20];
    __shared__ int   ssrc[16];
    __shared__ int   sdst[16];
    __shared__ float sm[16];

    int t = threadIdx.x;
    int ge0 = blockIdx.x * 16;
    int b  = ge0 >> 16;               // / EE
    int e0 = ge0 & (EE - 1);

    if (t < 16) {
        int s = edges[((size_t)b * EE + e0 + t) * 2 + 0];
        int d = edges[((size_t)b * EE + e0 + t) * 2 + 1];
        s = s < 0 ? 0 : (s > NN - 1 ? NN - 1 : s);
        d = d < 0 ? 0 : (d > NN - 1 ? NN - 1 : d);
        ssrc[t] = s;
        sdst[t] = d;
        sm[t]   = emask[(size_t)b * EE + e0 + t] ? 1.f : 0.f;
    }
    __syncthreads();

    // gather: h_src -> xs[0..127][e], h_dst -> xs[128..255][e]
    #pragma unroll
    for (int i = 0; i < 8; ++i) {
        int idx = i * 256 + t; int e = idx >> 7; int c = idx & 127;
        xs[c][e]       = hbuf[hrow(b, ssrc[e]) + c];
        xs[128 + c][e] = hbuf[hrow(b, sdst[e]) + c];
    }
    { // raw edge features: 16 edges x 16
        int e = t >> 4; int c = t & 15;
        xs[256 + c][e] = edge_feat[(size_t)(b * EE + e0 + e) * FE + c];
    }
    __syncthreads();

    int j   = t & 63;         // thread owns cols j and j+64
    int grp = t >> 6;         // wave id -> edge quad
    int eb  = grp * 4;

    float a0[4], a1[4];
    {
        float bb0 = b1[j], bb1 = b1[j + 64];
        #pragma unroll
        for (int i = 0; i < 4; ++i) { a0[i] = bb0; a1[i] = bb1; }
    }
    #pragma unroll 4
    for (int k = 0; k < 256; ++k) {
        float4 x = *(const float4*)&xs[k][eb];
        float wa = W1[k * HID + j];
        float wb = W1[k * HID + j + 64];
        a0[0] += x.x * wa; a0[1] += x.y * wa; a0[2] += x.z * wa; a0[3] += x.w * wa;
        a1[0] += x.x * wb; a1[1] += x.y * wb; a1[2] += x.z * wb; a1[3] += x.w * wb;
    }
    #pragma unroll
    for (int k = 0; k < 16; ++k) {
        float4 x = *(const float4*)&xs[256 + k][eb];
        float wa = Wec[k * HID + j];
        float wb = Wec[k * HID + j + 64];
        a0[0] += x.x * wa; a0[1] += x.y * wa; a0[2] += x.z * wa; a0[3] += x.w * wa;
        a1[0] += x.x * wb; a1[1] += x.y * wb; a1[2] += x.z * wb; a1[3] += x.w * wb;
    }
    { // silu -> ts (transposed)
        float4 s0, s1;
        s0.x = silu(a0[0]); s0.y = silu(a0[1]); s0.z = silu(a0[2]); s0.w = silu(a0[3]);
        s1.x = silu(a1[0]); s1.y = silu(a1[1]); s1.z = silu(a1[2]); s1.w = silu(a1[3]);
        *(float4*)&ts[j][eb]      = s0;
        *(float4*)&ts[j + 64][eb] = s1;
    }
    __syncthreads();

    float o0[4], o1[4];
    {
        float bb0 = b2[j], bb1 = b2[j + 64];
        #pragma unroll
        for (int i = 0; i < 4; ++i) { o0[i] = bb0; o1[i] = bb1; }
    }
    #pragma unroll 4
    for (int k = 0; k < 128; ++k) {
        float4 x = *(const float4*)&ts[k][eb];
        float wa = W2[k * HID + j];
        float wb = W2[k * HID + j + 64];
        o0[0] += x.x * wa; o0[1] += x.y * wa; o0[2] += x.z * wa; o0[3] += x.w * wa;
        o1[0] += x.x * wb; o1[1] += x.y * wb; o1[2] += x.z * wb; o1[3] += x.w * wb;
    }
    #pragma unroll
    for (int i = 0; i < 4; ++i) {
        int e = eb + i;
        if (sm[e] != 0.f) {     // wave-uniform branch (same e across wave)
            float* dp = &agg[(size_t)(b * NN + sdst[e]) * HID];
            atomicAdd(dp + j,      o0[i]);
            atomicAdd(dp + j + 64, o1[i]);
        }
    }
}

// ------- node MLP + residual + mask.  16 rows / block, IN-PLACE on hbuf ----
__global__ __launch_bounds__(256)
void node_kernel(float* __restrict__ hbuf,
                 const float* __restrict__ agg,
                 const int* __restrict__ nmask,
                 const float* __restrict__ W1,   // (256,128)
                 const float* __restrict__ b1,
                 const float* __restrict__ W2,   // (128,128)
                 const float* __restrict__ b2) {
    __shared__ float xs[256][20];
    __shared__ float ts[HID][20];
    int t = threadIdx.x;
    int row0 = blockIdx.x * 16;           // global node row; same b for all 16
    int b = row0 >> 12; int n0 = row0 & (NN - 1);
    #pragma unroll
    for (int i = 0; i < 8; ++i) {
        int idx = i * 256 + t; int e = idx >> 7; int c = idx & 127;
        xs[c][e]       = hbuf[hrow(b, n0 + e) + c];
        xs[128 + c][e] = agg[(size_t)(row0 + e) * HID + c];
    }
    __syncthreads();

    int j = t & 63; int grp = t >> 6; int eb = grp * 4;
    float a0[4], a1[4];
    {
        float bb0 = b1[j], bb1 = b1[j + 64];
        #pragma unroll
        for (int i = 0; i < 4; ++i) { a0[i] = bb0; a1[i] = bb1; }
    }
    #pragma unroll 4
    for (int k = 0; k < 256; ++k) {
        float4 x = *(const float4*)&xs[k][eb];
        float wa = W1[k * HID + j];
        float wb = W1[k * HID + j + 64];
        a0[0] += x.x * wa; a0[1] += x.y * wa; a0[2] += x.z * wa; a0[3] += x.w * wa;
        a1[0] += x.x * wb; a1[1] += x.y * wb; a1[2] += x.z * wb; a1[3] += x.w * wb;
    }
    {
        float4 s0, s1;
        s0.x = silu(a0[0]); s0.y = silu(a0[1]); s0.z = silu(a0[2]); s0.w = silu(a0[3]);
        s1.x = silu(a1[0]); s1.y = silu(a1[1]); s1.z = silu(a1[2]); s1.w = silu(a1[3]);
        *(float4*)&ts[j][eb]      = s0;
        *(float4*)&ts[j + 64][eb] = s1;
    }
    __syncthreads();

    float o0[4], o1[4];
    {
        float bb0 = b2[j], bb1 = b2[j + 64];
        #pragma unroll
        for (int i = 0; i < 4; ++i) { o0[i] = bb0; o1[i] = bb1; }
    }
    #pragma unroll 4
    for (int k = 0; k < 128; ++k) {
        float4 x = *(const float4*)&ts[k][eb];
        float wa = W2[k * HID + j];
        float wb = W2[k * HID + j + 64];
        o0[0] += x.x * wa; o0[1] += x.y * wa; o0[2] += x.z * wa; o0[3] += x.w * wa;
        o1[0] += x.x * wb; o1[1] += x.y * wb; o1[2] += x.z * wb; o1[3] += x.w * wb;
    }
    #pragma unroll
    for (int i = 0; i < 4; ++i) {
        int row = row0 + eb + i;
        float m = nmask[row] ? 1.f : 0.f;
        float h0 = xs[j][eb + i];        // h[row][j]
        float h1 = xs[j + 64][eb + i];   // h[row][j+64]
        size_t base = hrow(b, n0 + eb + i);
        hbuf[base + j]      = (h0 + o0[i]) * m;
        hbuf[base + j + 64] = (h1 + o1[i]) * m;
    }
}

extern "C" void kernel_launch(void* const* d_in, const int* in_sizes, int n_in,
                              void* d_out, int out_size, void* d_ws, size_t ws_size,
                              hipStream_t stream) {
    const float* nodes     = (const float*)d_in[0];
    const float* edge_feat = (const float*)d_in[1];
    const int*   edges     = (const int*)d_in[2];
    const int*   node_mask = (const int*)d_in[3];
    const int*   edge_mask = (const int*)d_in[4];
    const float* W_node    = (const float*)d_in[5];
    const float* W_edge    = (const float*)d_in[6];
    const float* marker    = (const float*)d_in[7];
    const float* eW1       = (const float*)d_in[8];
    const float* eb1       = (const float*)d_in[9];
    const float* eW2       = (const float*)d_in[10];
    const float* eb2       = (const float*)d_in[11];
    const float* nW1       = (const float*)d_in[12];
    const float* nb1       = (const float*)d_in[13];
    const float* nW2       = (const float*)d_in[14];
    const float* nb2       = (const float*)d_in[15];
    float* out = (float*)d_out;

    const size_t HN = (size_t)BB * NN * HID;   // 2,097,152 floats
    const size_t need = (HN + (size_t)NROUNDS * 16 * HID) * sizeof(float);
    if (ws_size < need) return;                // clean fail, not a fault

    float* agg = (float*)d_ws;
    float* Wec = agg + HN;                     // 3*16*128 floats

    proj_nodes_kernel<<<(BB * NN) / 8, 128, 0, stream>>>(nodes, W_node, out);
    fuse_wec_kernel<<<48, 128, 0, stream>>>(W_edge, eW1, Wec);
    marker_kernel<<<1, 512, 0, stream>>>(marker, out);

    for (int r = 0; r < NROUNDS; ++r) {
        hipMemsetAsync(agg, 0, HN * sizeof(float), stream);
        edge_kernel<<<(BB * EE) / 16, 256, 0, stream>>>(
            out, edge_feat, edges, edge_mask,
            eW1 + (size_t)r * 384 * HID,
            Wec + (size_t)r * 16 * HID,
            eb1 + r * HID,
            eW2 + (size_t)r * HID * HID,
            eb2 + r * HID,
            agg);
        node_kernel<<<(BB * NN) / 16, 256, 0, stream>>>(
            out, agg, node_mask,
            nW1 + (size_t)r * 256 * HID,
            nb1 + r * HID,
            nW2 + (size_t)r * HID * HID,
            nb2 + r * HID);
    }
}

// Round 4
// 455.658 us; speedup vs baseline: 3.5327x; 3.5327x over previous
//
#include <hip/hip_runtime.h>
#include <hip/hip_bf16.h>
#include <cstdint>
#include <cstddef>

#define BB 4
#define NN 4096
#define EE 65536
#define HID 128
#define FN 32
#define FE 16
#define NROUNDS 3

#define XP 296   // edge X row pitch (bf16): 288 data + 8 pad; 148 dw % 32 = 20 -> 2-way
#define XNP 264  // node X row pitch (bf16): 256 data + 8 pad; 132 dw % 32 = 4  -> 2-way
#define PP 136   // P row pitch (bf16): 128 data + 8 pad

typedef __attribute__((ext_vector_type(8))) short short8;
typedef __attribute__((ext_vector_type(4))) float f32x4;

// h lives inside d_out: node n of batch b at out[(b*(NN+1) + 1 + n)*HID + j].
__device__ __forceinline__ size_t hrow(int b, int n) {
    return ((size_t)b * (NN + 1) + 1 + n) * HID;
}

__device__ __forceinline__ short f2bf(float f) {   // RNE float->bf16
    union { float f; uint32_t u; } v; v.f = f;
    uint32_t r = v.u + 0x7FFFu + ((v.u >> 16) & 1u);
    return (short)(r >> 16);
}

__device__ __forceinline__ float silu(float x) {
    return x / (1.0f + expf(-x));
}

// ---------------- h0 = nodes @ W_node; writes fp32 h (in out) + bf16 shadow
__global__ void proj_nodes_kernel(const float* __restrict__ nodes,
                                  const float* __restrict__ Wn,
                                  float* __restrict__ hbuf,
                                  short* __restrict__ hbf) {
    __shared__ float nd[8][FN];
    int t = threadIdx.x;              // col j in [0,128)
    int row0 = blockIdx.x * 8;        // global node row (b*NN + n)
    for (int i = 0; i < 2; ++i) {
        int idx = i * 128 + t; int r = idx >> 5; int c = idx & 31;
        nd[r][c] = nodes[(size_t)(row0 + r) * FN + c];
    }
    __syncthreads();
    float acc[8] = {0.f,0.f,0.f,0.f,0.f,0.f,0.f,0.f};
    #pragma unroll
    for (int k = 0; k < FN; ++k) {
        float w = Wn[k * HID + t];
        #pragma unroll
        for (int r = 0; r < 8; ++r) acc[r] += nd[r][k] * w;
    }
    #pragma unroll
    for (int r = 0; r < 8; ++r) {
        int row = row0 + r; int b = row >> 12; int n = row & (NN - 1);
        hbuf[hrow(b, n) + t] = acc[r];
        hbf[(size_t)row * HID + t] = f2bf(acc[r]);
    }
}

// ---- Wec[r] = W_edge (16x128) @ eW1[r][256:384] (128x128) -> (16x128) fp32
__global__ void fuse_wec_kernel(const float* __restrict__ We,
                                const float* __restrict__ eW1,
                                float* __restrict__ Wec) {
    int t = threadIdx.x;              // col j
    int i = blockIdx.x & 15;          // raw edge-feat index
    int r = blockIdx.x >> 4;          // round
    const float* w1 = eW1 + ((size_t)r * 384 + 256) * HID;
    float acc = 0.f;
    for (int k = 0; k < HID; ++k)
        acc += We[i * HID + k] * w1[k * HID + t];
    Wec[((size_t)r * 16 + i) * HID + t] = acc;
}

// ---------------- marker rows of the output --------------------------------
__global__ void marker_kernel(const float* __restrict__ marker,
                              float* __restrict__ out) {
    int t = threadIdx.x;              // 512 threads: b = t>>7, j = t&127
    int b = t >> 7; int j = t & 127;
    out[((size_t)b * (NN + 1)) * HID + j] = marker[j];
}

// ---- generic weight pack: (R, K, 128) fp32 -> per-lane B-fragment bf16 ----
// blockIdx = (r*KT + kt)*8 + nt ; 64 threads.
// lane's 8 bf16 = B[kt*32 + (lane>>4)*8 + i][nt*16 + (lane&15)], contiguous.
__global__ void pack_w_kernel(const float* __restrict__ W,
                              short* __restrict__ P,
                              int KT, int rstrideW) {
    int lane = threadIdx.x;
    int nt = blockIdx.x & 7;
    int kt = (blockIdx.x >> 3) % KT;
    int r  = blockIdx.x / (8 * KT);
    const float* Wr = W + (size_t)r * rstrideW;
    int n  = nt * 16 + (lane & 15);
    int k0 = kt * 32 + (lane >> 4) * 8;
    short v[8];
    #pragma unroll
    for (int i = 0; i < 8; ++i) v[i] = f2bf(Wr[(size_t)(k0 + i) * HID + n]);
    size_t idx = (((size_t)(r * KT + kt) * 8 + nt) * 64 + lane) * 8;
    *(uint4*)&P[idx] = *(uint4*)v;
}

// ---- edge layer-1 pack: K=288 = eW1 rows 0..255 | Wec rows 0..15 | zeros --
__global__ void pack_e1_kernel(const float* __restrict__ eW1,
                               const float* __restrict__ Wec,
                               short* __restrict__ P) {
    const int KT = 9;
    int lane = threadIdx.x;
    int nt = blockIdx.x & 7;
    int kt = (blockIdx.x >> 3) % KT;
    int r  = blockIdx.x / (8 * KT);
    int n  = nt * 16 + (lane & 15);
    int k0 = kt * 32 + (lane >> 4) * 8;
    short v[8];
    #pragma unroll
    for (int i = 0; i < 8; ++i) {
        int k = k0 + i;
        float x;
        if (k < 256)      x = eW1[((size_t)r * 384 + k) * HID + n];
        else if (k < 272) x = Wec[((size_t)r * 16 + (k - 256)) * HID + n];
        else              x = 0.f;
        v[i] = f2bf(x);
    }
    size_t idx = (((size_t)(r * KT + kt) * 8 + nt) * 64 + lane) * 8;
    *(uint4*)&P[idx] = *(uint4*)v;
}

// ------------- edge MLP (MFMA) + scatter-add.  64 edges / block ------------
__global__ __launch_bounds__(256, 4)
void edge_mfma_kernel(const short* __restrict__ hbf,
                      const float* __restrict__ edge_feat,
                      const int* __restrict__ edges,
                      const int* __restrict__ emask,
                      const short* __restrict__ W1p,  // packed, this round
                      const short* __restrict__ W2p,
                      const float* __restrict__ b1,
                      const float* __restrict__ b2,
                      float* __restrict__ agg) {
    __shared__ short X[64 * XP];      // P (64*PP) aliased over X between barriers
    __shared__ int ssrc[64];
    __shared__ int sdst[64];
    __shared__ int smk[64];
    short* Pl = X;

    int t = threadIdx.x;
    int ge0 = blockIdx.x * 64;
    int b  = ge0 >> 16;
    int e0 = ge0 & (EE - 1);

    if (t < 64) {
        int2 p = *(const int2*)&edges[((size_t)b * EE + e0 + t) * 2];
        int s = p.x < 0 ? 0 : (p.x > NN - 1 ? NN - 1 : p.x);
        int d = p.y < 0 ? 0 : (p.y > NN - 1 ? NN - 1 : p.y);
        ssrc[t] = s; sdst[t] = d;
        smk[t]  = emask[(size_t)b * EE + e0 + t];
    }
    __syncthreads();

    // stage h_src (cols 0..127): 64 rows x 16 chunks of 16B
    #pragma unroll
    for (int i = 0; i < 4; ++i) {
        int c = i * 256 + t; int e = c >> 4; int s = c & 15;
        uint4 v = *(const uint4*)(hbf + ((size_t)b * NN + ssrc[e]) * HID + s * 8);
        *(uint4*)((char*)X + e * (XP * 2) + s * 16) = v;
    }
    // stage h_dst (cols 128..255)
    #pragma unroll
    for (int i = 0; i < 4; ++i) {
        int c = i * 256 + t; int e = c >> 4; int s = c & 15;
        uint4 v = *(const uint4*)(hbf + ((size_t)b * NN + sdst[e]) * HID + s * 8);
        *(uint4*)((char*)X + e * (XP * 2) + 256 + s * 16) = v;
    }
    {   // edge features fp32 -> bf16, cols 256..271
        int e = t >> 2; int s = t & 3;
        float4 f = *(const float4*)(edge_feat + ((size_t)b * EE + e0 + e) * FE + s * 4);
        short v[4] = { f2bf(f.x), f2bf(f.y), f2bf(f.z), f2bf(f.w) };
        *(uint2*)((char*)X + e * (XP * 2) + 512 + s * 8) = *(uint2*)v;
    }
    if (t < 128) {  // zero K-pad cols 272..287 (avoid NaN*0 from stale LDS)
        int e = t >> 1; int s = t & 1;
        *(uint4*)((char*)X + e * (XP * 2) + 544 + s * 16) = make_uint4(0,0,0,0);
    }
    __syncthreads();

    int lane = t & 63;
    int w    = t >> 6;
    int m0 = (w & 1) * 32;          // wave's edge-row base
    int n0 = (w >> 1) * 64;         // wave's col base
    int lr = lane & 15;
    int lg = lane >> 4;

    // ---------------- layer 1: (64x288) @ (288x128) ----------------
    f32x4 acc[2][4];
    #pragma unroll
    for (int nf = 0; nf < 4; ++nf) {
        float bv = b1[n0 + nf * 16 + lr];
        #pragma unroll
        for (int mf = 0; mf < 2; ++mf)
            acc[mf][nf] = (f32x4){bv, bv, bv, bv};
    }
    const char* Xb = (const char*)X;
    for (int kt = 0; kt < 9; ++kt) {
        short8 a[2];
        #pragma unroll
        for (int mf = 0; mf < 2; ++mf)
            a[mf] = *(const short8*)(Xb + (m0 + mf * 16 + lr) * (XP * 2)
                                        + (kt * 32 + lg * 8) * 2);
        const short* wp = W1p + (((size_t)kt * 8 + (n0 >> 4)) * 64 + lane) * 8;
        #pragma unroll
        for (int nf = 0; nf < 4; ++nf) {
            short8 bf = *(const short8*)(wp + (size_t)nf * 64 * 8);
            #pragma unroll
            for (int mf = 0; mf < 2; ++mf)
                acc[mf][nf] = __builtin_amdgcn_mfma_f32_16x16x32_bf16(
                    a[mf], bf, acc[mf][nf], 0, 0, 0);
        }
    }
    __syncthreads();   // all waves done reading X; safe to overwrite with P

    // silu -> P (bf16), C/D layout: col = lane&15, row = (lane>>4)*4 + reg
    #pragma unroll
    for (int mf = 0; mf < 2; ++mf)
        #pragma unroll
        for (int nf = 0; nf < 4; ++nf)
            #pragma unroll
            for (int r = 0; r < 4; ++r) {
                float v = acc[mf][nf][r];
                int row = m0 + mf * 16 + lg * 4 + r;
                int col = n0 + nf * 16 + lr;
                Pl[row * PP + col] = f2bf(silu(v));
            }
    __syncthreads();

    // ---------------- layer 2: (64x128) @ (128x128) ----------------
    f32x4 acc2[2][4];
    #pragma unroll
    for (int nf = 0; nf < 4; ++nf) {
        float bv = b2[n0 + nf * 16 + lr];
        #pragma unroll
        for (int mf = 0; mf < 2; ++mf)
            acc2[mf][nf] = (f32x4){bv, bv, bv, bv};
    }
    const char* Pb = (const char*)Pl;
    for (int kt = 0; kt < 4; ++kt) {
        short8 a[2];
        #pragma unroll
        for (int mf = 0; mf < 2; ++mf)
            a[mf] = *(const short8*)(Pb + (m0 + mf * 16 + lr) * (PP * 2)
                                        + (kt * 32 + lg * 8) * 2);
        const short* wp = W2p + (((size_t)kt * 8 + (n0 >> 4)) * 64 + lane) * 8;
        #pragma unroll
        for (int nf = 0; nf < 4; ++nf) {
            short8 bf = *(const short8*)(wp + (size_t)nf * 64 * 8);
            #pragma unroll
            for (int mf = 0; mf < 2; ++mf)
                acc2[mf][nf] = __builtin_amdgcn_mfma_f32_16x16x32_bf16(
                    a[mf], bf, acc2[mf][nf], 0, 0, 0);
        }
    }

    // masked atomic scatter to agg
    #pragma unroll
    for (int mf = 0; mf < 2; ++mf)
        #pragma unroll
        for (int r = 0; r < 4; ++r) {
            int e = m0 + mf * 16 + lg * 4 + r;
            if (smk[e]) {
                float* dp = agg + ((size_t)b * NN + sdst[e]) * HID + n0 + lr;
                #pragma unroll
                for (int nf = 0; nf < 4; ++nf)
                    atomicAdd(dp + nf * 16, acc2[mf][nf][r]);
            }
        }
}

// ------------- node MLP (MFMA) + residual + mask.  64 rows / block ---------
__global__ __launch_bounds__(256, 4)
void node_mfma_kernel(const short* __restrict__ hbf_in,
                      const float* __restrict__ agg,
                      const int* __restrict__ nmask,
                      const short* __restrict__ W1p,
                      const short* __restrict__ W2p,
                      const float* __restrict__ b1,
                      const float* __restrict__ b2,
                      float* __restrict__ hout,     // fp32 h (in out buffer)
                      short* __restrict__ hbf_out) {
    __shared__ short X[64 * XNP];     // P aliased over X
    __shared__ int smk[64];
    short* Pl = X;

    int t = threadIdx.x;
    int row0 = blockIdx.x * 64;       // global node row; same b for all 64
    int b  = row0 >> 12;
    int nn0 = row0 & (NN - 1);

    if (t < 64) smk[t] = nmask[row0 + t];

    // stage h (bf16) cols 0..127: 64 rows x 16 chunks of 16B
    #pragma unroll
    for (int i = 0; i < 4; ++i) {
        int c = i * 256 + t; int e = c >> 4; int s = c & 15;
        uint4 v = *(const uint4*)(hbf_in + (size_t)(row0 + e) * HID + s * 8);
        *(uint4*)((char*)X + e * (XNP * 2) + s * 16) = v;
    }
    // stage agg fp32 -> bf16 cols 128..255
    #pragma unroll
    for (int i = 0; i < 8; ++i) {
        int c = i * 256 + t; int e = c >> 5; int s = c & 31;
        float4 f = *(const float4*)(agg + (size_t)(row0 + e) * HID + s * 4);
        short v[4] = { f2bf(f.x), f2bf(f.y), f2bf(f.z), f2bf(f.w) };
        *(uint2*)((char*)X + e * (XNP * 2) + 256 + s * 8) = *(uint2*)v;
    }
    __syncthreads();

    int lane = t & 63;
    int w    = t >> 6;
    int m0 = (w & 1) * 32;
    int n0 = (w >> 1) * 64;
    int lr = lane & 15;
    int lg = lane >> 4;

    f32x4 acc[2][4];
    #pragma unroll
    for (int nf = 0; nf < 4; ++nf) {
        float bv = b1[n0 + nf * 16 + lr];
        #pragma unroll
        for (int mf = 0; mf < 2; ++mf)
            acc[mf][nf] = (f32x4){bv, bv, bv, bv};
    }
    const char* Xb = (const char*)X;
    for (int kt = 0; kt < 8; ++kt) {
        short8 a[2];
        #pragma unroll
        for (int mf = 0; mf < 2; ++mf)
            a[mf] = *(const short8*)(Xb + (m0 + mf * 16 + lr) * (XNP * 2)
                                        + (kt * 32 + lg * 8) * 2);
        const short* wp = W1p + (((size_t)kt * 8 + (n0 >> 4)) * 64 + lane) * 8;
        #pragma unroll
        for (int nf = 0; nf < 4; ++nf) {
            short8 bf = *(const short8*)(wp + (size_t)nf * 64 * 8);
            #pragma unroll
            for (int mf = 0; mf < 2; ++mf)
                acc[mf][nf] = __builtin_amdgcn_mfma_f32_16x16x32_bf16(
                    a[mf], bf, acc[mf][nf], 0, 0, 0);
        }
    }
    __syncthreads();

    #pragma unroll
    for (int mf = 0; mf < 2; ++mf)
        #pragma unroll
        for (int nf = 0; nf < 4; ++nf)
            #pragma unroll
            for (int r = 0; r < 4; ++r) {
                float v = acc[mf][nf][r];
                int row = m0 + mf * 16 + lg * 4 + r;
                int col = n0 + nf * 16 + lr;
                Pl[row * PP + col] = f2bf(silu(v));
            }
    __syncthreads();

    f32x4 acc2[2][4];
    #pragma unroll
    for (int nf = 0; nf < 4; ++nf) {
        float bv = b2[n0 + nf * 16 + lr];
        #pragma unroll
        for (int mf = 0; mf < 2; ++mf)
            acc2[mf][nf] = (f32x4){bv, bv, bv, bv};
    }
    const char* Pb = (const char*)Pl;
    for (int kt = 0; kt < 4; ++kt) {
        short8 a[2];
        #pragma unroll
        for (int mf = 0; mf < 2; ++mf)
            a[mf] = *(const short8*)(Pb + (m0 + mf * 16 + lr) * (PP * 2)
                                        + (kt * 32 + lg * 8) * 2);
        const short* wp = W2p + (((size_t)kt * 8 + (n0 >> 4)) * 64 + lane) * 8;
        #pragma unroll
        for (int nf = 0; nf < 4; ++nf) {
            short8 bf = *(const short8*)(wp + (size_t)nf * 64 * 8);
            #pragma unroll
            for (int mf = 0; mf < 2; ++mf)
                acc2[mf][nf] = __builtin_amdgcn_mfma_f32_16x16x32_bf16(
                    a[mf], bf, acc2[mf][nf], 0, 0, 0);
        }
    }

    // epilogue: h_new = (h_old_fp32 + upd) * mask; write fp32 + bf16 shadow
    #pragma unroll
    for (int mf = 0; mf < 2; ++mf)
        #pragma unroll
        for (int r = 0; r < 4; ++r) {
            int rl = m0 + mf * 16 + lg * 4 + r;
            float m = smk[rl] ? 1.f : 0.f;
            size_t ho = hrow(b, nn0 + rl);
            size_t hb = (size_t)(row0 + rl) * HID;
            #pragma unroll
            for (int nf = 0; nf < 4; ++nf) {
                int col = n0 + nf * 16 + lr;
                float hold = hout[ho + col];
                float hn = (hold + acc2[mf][nf][r]) * m;
                hout[ho + col] = hn;
                hbf_out[hb + col] = f2bf(hn);
            }
        }
}

extern "C" void kernel_launch(void* const* d_in, const int* in_sizes, int n_in,
                              void* d_out, int out_size, void* d_ws, size_t ws_size,
                              hipStream_t stream) {
    const float* nodes     = (const float*)d_in[0];
    const float* edge_feat = (const float*)d_in[1];
    const int*   edges     = (const int*)d_in[2];
    const int*   node_mask = (const int*)d_in[3];
    const int*   edge_mask = (const int*)d_in[4];
    const float* W_node    = (const float*)d_in[5];
    const float* W_edge    = (const float*)d_in[6];
    const float* marker    = (const float*)d_in[7];
    const float* eW1       = (const float*)d_in[8];
    const float* eb1       = (const float*)d_in[9];
    const float* eW2       = (const float*)d_in[10];
    const float* eb2       = (const float*)d_in[11];
    const float* nW1       = (const float*)d_in[12];
    const float* nb1       = (const float*)d_in[13];
    const float* nW2       = (const float*)d_in[14];
    const float* nb2       = (const float*)d_in[15];
    float* out = (float*)d_out;

    const size_t HN = (size_t)BB * NN * HID;        // 2,097,152
    char* wsb = (char*)d_ws;
    float* agg  = (float*)wsb;                         wsb += HN * 4;
    short* hbf  = (short*)wsb;                         wsb += HN * 2;
    float* Wec  = (float*)wsb;                         wsb += 3 * 16 * HID * 4;
    short* W1p  = (short*)wsb;                         wsb += 3 * 9 * 4096 * 2;
    short* W2p  = (short*)wsb;                         wsb += 3 * 4 * 4096 * 2;
    short* nW1p = (short*)wsb;                         wsb += 3 * 8 * 4096 * 2;
    short* nW2p = (short*)wsb;                         wsb += 3 * 4 * 4096 * 2;
    if ((size_t)(wsb - (char*)d_ws) > ws_size) return;  // clean fail

    proj_nodes_kernel<<<(BB * NN) / 8, 128, 0, stream>>>(nodes, W_node, out, hbf);
    fuse_wec_kernel<<<48, 128, 0, stream>>>(W_edge, eW1, Wec);
    marker_kernel<<<1, 512, 0, stream>>>(marker, out);
    pack_e1_kernel<<<3 * 9 * 8, 64, 0, stream>>>(eW1, Wec, W1p);
    pack_w_kernel<<<3 * 4 * 8, 64, 0, stream>>>(eW2, W2p, 4, HID * HID);
    pack_w_kernel<<<3 * 8 * 8, 64, 0, stream>>>(nW1, nW1p, 8, 2 * HID * HID);
    pack_w_kernel<<<3 * 4 * 8, 64, 0, stream>>>(nW2, nW2p, 4, HID * HID);

    for (int r = 0; r < NROUNDS; ++r) {
        hipMemsetAsync(agg, 0, HN * sizeof(float), stream);
        edge_mfma_kernel<<<(BB * EE) / 64, 256, 0, stream>>>(
            hbf, edge_feat, edges, edge_mask,
            W1p + (size_t)r * 9 * 4096,
            W2p + (size_t)r * 4 * 4096,
            eb1 + r * HID,
            eb2 + r * HID,
            agg);
        node_mfma_kernel<<<(BB * NN) / 64, 256, 0, stream>>>(
            hbf, agg, node_mask,
            nW1p + (size_t)r * 8 * 4096,
            nW2p + (size_t)r * 4 * 4096,
            nb1 + r * HID,
            nb2 + r * HID,
            out, hbf);
    }
}

// Round 5
// 295.073 us; speedup vs baseline: 5.4552x; 1.5442x over previous
//
#include <hip/hip_runtime.h>
#include <hip/hip_bf16.h>
#include <cstdint>
#include <cstddef>

#define BB 4
#define NN 4096
#define EE 65536
#define HID 128
#define FN 32
#define FE 16
#define NROUNDS 3

#define XP 296   // edge X row pitch (bf16): 288 data + 8 pad
#define XNP 264  // node X row pitch (bf16): 256 data + 8 pad
#define PP 136   // P row pitch (bf16): 128 data + 8 pad
#define RP 132   // reduction tile row pitch (fp32): 128 data + 4 pad

typedef __attribute__((ext_vector_type(8))) short short8;
typedef __attribute__((ext_vector_type(4))) float f32x4;
typedef unsigned int uint_t;

// h lives inside d_out: node n of batch b at out[(b*(NN+1) + 1 + n)*HID + j].
__device__ __forceinline__ size_t hrow(int b, int n) {
    return ((size_t)b * (NN + 1) + 1 + n) * HID;
}

__device__ __forceinline__ short f2bf(float f) {   // RNE float->bf16
    union { float f; uint32_t u; } v; v.f = f;
    uint32_t r = v.u + 0x7FFFu + ((v.u >> 16) & 1u);
    return (short)(r >> 16);
}

__device__ __forceinline__ float silu(float x) {
    return x / (1.0f + expf(-x));
}

__device__ __forceinline__ int clipn(int x) {
    return x < 0 ? 0 : (x > NN - 1 ? NN - 1 : x);
}

// ---------------- h0 = nodes @ W_node; writes fp32 h (in out) + bf16 shadow
__global__ void proj_nodes_kernel(const float* __restrict__ nodes,
                                  const float* __restrict__ Wn,
                                  float* __restrict__ hbuf,
                                  short* __restrict__ hbf) {
    __shared__ float nd[8][FN];
    int t = threadIdx.x;
    int row0 = blockIdx.x * 8;
    for (int i = 0; i < 2; ++i) {
        int idx = i * 128 + t; int r = idx >> 5; int c = idx & 31;
        nd[r][c] = nodes[(size_t)(row0 + r) * FN + c];
    }
    __syncthreads();
    float acc[8] = {0.f,0.f,0.f,0.f,0.f,0.f,0.f,0.f};
    #pragma unroll
    for (int k = 0; k < FN; ++k) {
        float w = Wn[k * HID + t];
        #pragma unroll
        for (int r = 0; r < 8; ++r) acc[r] += nd[r][k] * w;
    }
    #pragma unroll
    for (int r = 0; r < 8; ++r) {
        int row = row0 + r; int b = row >> 12; int n = row & (NN - 1);
        hbuf[hrow(b, n) + t] = acc[r];
        hbf[(size_t)row * HID + t] = f2bf(acc[r]);
    }
}

// ---- Wec[r] = W_edge (16x128) @ eW1[r][256:384] (128x128) -> (16x128) fp32
__global__ void fuse_wec_kernel(const float* __restrict__ We,
                                const float* __restrict__ eW1,
                                float* __restrict__ Wec) {
    int t = threadIdx.x;
    int i = blockIdx.x & 15;
    int r = blockIdx.x >> 4;
    const float* w1 = eW1 + ((size_t)r * 384 + 256) * HID;
    float acc = 0.f;
    for (int k = 0; k < HID; ++k)
        acc += We[i * HID + k] * w1[k * HID + t];
    Wec[((size_t)r * 16 + i) * HID + t] = acc;
}

// ---------------- marker rows of the output --------------------------------
__global__ void marker_kernel(const float* __restrict__ marker,
                              float* __restrict__ out) {
    int t = threadIdx.x;
    int b = t >> 7; int j = t & 127;
    out[((size_t)b * (NN + 1)) * HID + j] = marker[j];
}

// ---- generic weight pack: (R, K, 128) fp32 -> per-lane B-fragment bf16 ----
__global__ void pack_w_kernel(const float* __restrict__ W,
                              short* __restrict__ P,
                              int KT, int rstrideW) {
    int lane = threadIdx.x;
    int nt = blockIdx.x & 7;
    int kt = (blockIdx.x >> 3) % KT;
    int r  = blockIdx.x / (8 * KT);
    const float* Wr = W + (size_t)r * rstrideW;
    int n  = nt * 16 + (lane & 15);
    int k0 = kt * 32 + (lane >> 4) * 8;
    short v[8];
    #pragma unroll
    for (int i = 0; i < 8; ++i) v[i] = f2bf(Wr[(size_t)(k0 + i) * HID + n]);
    size_t idx = (((size_t)(r * KT + kt) * 8 + nt) * 64 + lane) * 8;
    *(uint4*)&P[idx] = *(uint4*)v;
}

// ---- edge layer-1 pack: K=288 = eW1 rows 0..255 | Wec rows 0..15 | zeros --
__global__ void pack_e1_kernel(const float* __restrict__ eW1,
                               const float* __restrict__ Wec,
                               short* __restrict__ P) {
    const int KT = 9;
    int lane = threadIdx.x;
    int nt = blockIdx.x & 7;
    int kt = (blockIdx.x >> 3) % KT;
    int r  = blockIdx.x / (8 * KT);
    int n  = nt * 16 + (lane & 15);
    int k0 = kt * 32 + (lane >> 4) * 8;
    short v[8];
    #pragma unroll
    for (int i = 0; i < 8; ++i) {
        int k = k0 + i;
        float x;
        if (k < 256)      x = eW1[((size_t)r * 384 + k) * HID + n];
        else if (k < 272) x = Wec[((size_t)r * 16 + (k - 256)) * HID + n];
        else              x = 0.f;
        v[i] = f2bf(x);
    }
    size_t idx = (((size_t)(r * KT + kt) * 8 + nt) * 64 + lane) * 8;
    *(uint4*)&P[idx] = *(uint4*)v;
}

// ================= counting sort of edges by (b, dst) ======================
__global__ void hist_kernel(const int* __restrict__ edges,
                            uint_t* __restrict__ cnt) {
    int i = blockIdx.x * 256 + threadIdx.x;        // global edge id
    int b = i >> 16;
    int d = clipn(edges[(size_t)i * 2 + 1]);
    atomicAdd(&cnt[b * NN + d], 1u);
}

// one block, 256 threads: exclusive scan of 16384 counts -> cursor
__global__ void scan_kernel(const uint_t* __restrict__ cnt,
                            uint_t* __restrict__ cursor) {
    __shared__ uint_t ps[256];
    int t = threadIdx.x;
    int base = t * 64;
    uint_t s = 0;
    for (int i = 0; i < 64; ++i) s += cnt[base + i];
    ps[t] = s;
    __syncthreads();
    for (int off = 1; off < 256; off <<= 1) {
        uint_t v = (t >= off) ? ps[t - off] : 0u;
        __syncthreads();
        ps[t] += v;
        __syncthreads();
    }
    uint_t run = ps[t] - s;          // exclusive offset for this thread's span
    for (int i = 0; i < 64; ++i) {
        cursor[base + i] = run;
        run += cnt[base + i];
    }
}

__global__ void scatter_kernel(const int* __restrict__ edges,
                               uint_t* __restrict__ cursor,
                               uint_t* __restrict__ eidx) {
    int i = blockIdx.x * 256 + threadIdx.x;        // global edge id
    int b = i >> 16;
    int d = clipn(edges[(size_t)i * 2 + 1]);
    uint_t p = atomicAdd(&cursor[b * NN + d], 1u);
    eidx[p] = (uint_t)(i & (EE - 1));              // batch-local edge index
}

// ===== edge MLP (MFMA) over dst-sorted edges + segment-reduced scatter =====
__global__ __launch_bounds__(256, 4)
void edge_mfma_csr_kernel(const short* __restrict__ hbf,
                          const float* __restrict__ edge_feat,
                          const int* __restrict__ edges,
                          const int* __restrict__ emask,
                          const uint_t* __restrict__ eidx,
                          const short* __restrict__ W1p,
                          const short* __restrict__ W2p,
                          const float* __restrict__ b1,
                          const float* __restrict__ b2,
                          float* __restrict__ agg) {
    // one buffer, three aliased phases: X (bf16 64xXP) -> P (bf16 64xPP)
    //                                   -> Rt (fp32 64xRP)
    __shared__ short X[64 * XP];                   // 37888 B
    __shared__ int ssrc[64];
    __shared__ int sdst[64];
    __shared__ float smf[64];
    __shared__ int seid[64];
    short* Pl = X;
    float* Rt = (float*)X;

    int t = threadIdx.x;
    int p0 = blockIdx.x * 64;                      // sorted-position base
    int b  = p0 >> 16;

    if (t < 64) {
        int e = (int)eidx[p0 + t];
        seid[t] = e;
        int2 pr = *(const int2*)&edges[((size_t)b * EE + e) * 2];
        ssrc[t] = clipn(pr.x);
        sdst[t] = clipn(pr.y);
        smf[t]  = emask[(size_t)b * EE + e] ? 1.f : 0.f;
    }
    __syncthreads();

    // stage h_src (cols 0..127): 64 rows x 16 chunks of 16B
    #pragma unroll
    for (int i = 0; i < 4; ++i) {
        int c = i * 256 + t; int e = c >> 4; int s = c & 15;
        uint4 v = *(const uint4*)(hbf + ((size_t)b * NN + ssrc[e]) * HID + s * 8);
        *(uint4*)((char*)X + e * (XP * 2) + s * 16) = v;
    }
    // stage h_dst (cols 128..255) — sorted: consecutive rows often same dst
    #pragma unroll
    for (int i = 0; i < 4; ++i) {
        int c = i * 256 + t; int e = c >> 4; int s = c & 15;
        uint4 v = *(const uint4*)(hbf + ((size_t)b * NN + sdst[e]) * HID + s * 8);
        *(uint4*)((char*)X + e * (XP * 2) + 256 + s * 16) = v;
    }
    {   // edge features fp32 -> bf16, cols 256..271 (permuted rows via seid)
        int e = t >> 2; int s = t & 3;
        float4 f = *(const float4*)(edge_feat
                      + ((size_t)b * EE + seid[e]) * FE + s * 4);
        short v[4] = { f2bf(f.x), f2bf(f.y), f2bf(f.z), f2bf(f.w) };
        *(uint2*)((char*)X + e * (XP * 2) + 512 + s * 8) = *(uint2*)v;
    }
    if (t < 128) {  // zero K-pad cols 272..287
        int e = t >> 1; int s = t & 1;
        *(uint4*)((char*)X + e * (XP * 2) + 544 + s * 16) = make_uint4(0,0,0,0);
    }
    __syncthreads();

    int lane = t & 63;
    int w    = t >> 6;
    int m0 = (w & 1) * 32;
    int n0 = (w >> 1) * 64;
    int lr = lane & 15;
    int lg = lane >> 4;

    // ---------------- layer 1: (64x288) @ (288x128) ----------------
    f32x4 acc[2][4];
    #pragma unroll
    for (int nf = 0; nf < 4; ++nf) {
        float bv = b1[n0 + nf * 16 + lr];
        #pragma unroll
        for (int mf = 0; mf < 2; ++mf)
            acc[mf][nf] = (f32x4){bv, bv, bv, bv};
    }
    const char* Xb = (const char*)X;
    for (int kt = 0; kt < 9; ++kt) {
        short8 a[2];
        #pragma unroll
        for (int mf = 0; mf < 2; ++mf)
            a[mf] = *(const short8*)(Xb + (m0 + mf * 16 + lr) * (XP * 2)
                                        + (kt * 32 + lg * 8) * 2);
        const short* wp = W1p + (((size_t)kt * 8 + (n0 >> 4)) * 64 + lane) * 8;
        #pragma unroll
        for (int nf = 0; nf < 4; ++nf) {
            short8 bf = *(const short8*)(wp + (size_t)nf * 64 * 8);
            #pragma unroll
            for (int mf = 0; mf < 2; ++mf)
                acc[mf][nf] = __builtin_amdgcn_mfma_f32_16x16x32_bf16(
                    a[mf], bf, acc[mf][nf], 0, 0, 0);
        }
    }
    __syncthreads();   // done reading X; overwrite with P

    #pragma unroll
    for (int mf = 0; mf < 2; ++mf)
        #pragma unroll
        for (int nf = 0; nf < 4; ++nf)
            #pragma unroll
            for (int r = 0; r < 4; ++r) {
                int row = m0 + mf * 16 + lg * 4 + r;
                int col = n0 + nf * 16 + lr;
                Pl[row * PP + col] = f2bf(silu(acc[mf][nf][r]));
            }
    __syncthreads();

    // ---------------- layer 2: (64x128) @ (128x128) ----------------
    f32x4 acc2[2][4];
    #pragma unroll
    for (int nf = 0; nf < 4; ++nf) {
        float bv = b2[n0 + nf * 16 + lr];
        #pragma unroll
        for (int mf = 0; mf < 2; ++mf)
            acc2[mf][nf] = (f32x4){bv, bv, bv, bv};
    }
    const char* Pb = (const char*)Pl;
    for (int kt = 0; kt < 4; ++kt) {
        short8 a[2];
        #pragma unroll
        for (int mf = 0; mf < 2; ++mf)
            a[mf] = *(const short8*)(Pb + (m0 + mf * 16 + lr) * (PP * 2)
                                        + (kt * 32 + lg * 8) * 2);
        const short* wp = W2p + (((size_t)kt * 8 + (n0 >> 4)) * 64 + lane) * 8;
        #pragma unroll
        for (int nf = 0; nf < 4; ++nf) {
            short8 bf = *(const short8*)(wp + (size_t)nf * 64 * 8);
            #pragma unroll
            for (int mf = 0; mf < 2; ++mf)
                acc2[mf][nf] = __builtin_amdgcn_mfma_f32_16x16x32_bf16(
                    a[mf], bf, acc2[mf][nf], 0, 0, 0);
        }
    }
    __syncthreads();   // done reading P; overwrite with Rt (fp32 msg tile)

    #pragma unroll
    for (int mf = 0; mf < 2; ++mf)
        #pragma unroll
        for (int r = 0; r < 4; ++r) {
            int row = m0 + mf * 16 + lg * 4 + r;
            float m = smf[row];
            #pragma unroll
            for (int nf = 0; nf < 4; ++nf)
                Rt[row * RP + n0 + nf * 16 + lr] = acc2[mf][nf][r] * m;
        }
    __syncthreads();

    // segment-reduce contiguous same-dst rows; one atomic per segment
    {
        int half = t >> 7;            // rows 0..31 or 32..63
        int c    = t & 127;
        int r0 = half * 32, r1 = r0 + 32;
        float run = 0.f;
        int cur = sdst[r0];
        for (int r = r0; r < r1; ++r) {
            int d = sdst[r];          // wave-uniform (same rows across lanes)
            if (d != cur) {
                atomicAdd(&agg[((size_t)b * NN + cur) * HID + c], run);
                run = 0.f; cur = d;
            }
            run += Rt[r * RP + c];
        }
        atomicAdd(&agg[((size_t)b * NN + cur) * HID + c], run);
    }
}

// ------------- node MLP (MFMA) + residual + mask.  64 rows / block ---------
__global__ __launch_bounds__(256, 4)
void node_mfma_kernel(const short* __restrict__ hbf_in,
                      const float* __restrict__ agg,
                      const int* __restrict__ nmask,
                      const short* __restrict__ W1p,
                      const short* __restrict__ W2p,
                      const float* __restrict__ b1,
                      const float* __restrict__ b2,
                      float* __restrict__ hout,
                      short* __restrict__ hbf_out) {
    __shared__ short X[64 * XNP];
    __shared__ int smk[64];
    short* Pl = X;

    int t = threadIdx.x;
    int row0 = blockIdx.x * 64;
    int b  = row0 >> 12;
    int nn0 = row0 & (NN - 1);

    if (t < 64) smk[t] = nmask[row0 + t];

    #pragma unroll
    for (int i = 0; i < 4; ++i) {
        int c = i * 256 + t; int e = c >> 4; int s = c & 15;
        uint4 v = *(const uint4*)(hbf_in + (size_t)(row0 + e) * HID + s * 8);
        *(uint4*)((char*)X + e * (XNP * 2) + s * 16) = v;
    }
    #pragma unroll
    for (int i = 0; i < 8; ++i) {
        int c = i * 256 + t; int e = c >> 5; int s = c & 31;
        float4 f = *(const float4*)(agg + (size_t)(row0 + e) * HID + s * 4);
        short v[4] = { f2bf(f.x), f2bf(f.y), f2bf(f.z), f2bf(f.w) };
        *(uint2*)((char*)X + e * (XNP * 2) + 256 + s * 8) = *(uint2*)v;
    }
    __syncthreads();

    int lane = t & 63;
    int w    = t >> 6;
    int m0 = (w & 1) * 32;
    int n0 = (w >> 1) * 64;
    int lr = lane & 15;
    int lg = lane >> 4;

    f32x4 acc[2][4];
    #pragma unroll
    for (int nf = 0; nf < 4; ++nf) {
        float bv = b1[n0 + nf * 16 + lr];
        #pragma unroll
        for (int mf = 0; mf < 2; ++mf)
            acc[mf][nf] = (f32x4){bv, bv, bv, bv};
    }
    const char* Xb = (const char*)X;
    for (int kt = 0; kt < 8; ++kt) {
        short8 a[2];
        #pragma unroll
        for (int mf = 0; mf < 2; ++mf)
            a[mf] = *(const short8*)(Xb + (m0 + mf * 16 + lr) * (XNP * 2)
                                        + (kt * 32 + lg * 8) * 2);
        const short* wp = W1p + (((size_t)kt * 8 + (n0 >> 4)) * 64 + lane) * 8;
        #pragma unroll
        for (int nf = 0; nf < 4; ++nf) {
            short8 bf = *(const short8*)(wp + (size_t)nf * 64 * 8);
            #pragma unroll
            for (int mf = 0; mf < 2; ++mf)
                acc[mf][nf] = __builtin_amdgcn_mfma_f32_16x16x32_bf16(
                    a[mf], bf, acc[mf][nf], 0, 0, 0);
        }
    }
    __syncthreads();

    #pragma unroll
    for (int mf = 0; mf < 2; ++mf)
        #pragma unroll
        for (int nf = 0; nf < 4; ++nf)
            #pragma unroll
            for (int r = 0; r < 4; ++r) {
                int row = m0 + mf * 16 + lg * 4 + r;
                int col = n0 + nf * 16 + lr;
                Pl[row * PP + col] = f2bf(silu(acc[mf][nf][r]));
            }
    __syncthreads();

    f32x4 acc2[2][4];
    #pragma unroll
    for (int nf = 0; nf < 4; ++nf) {
        float bv = b2[n0 + nf * 16 + lr];
        #pragma unroll
        for (int mf = 0; mf < 2; ++mf)
            acc2[mf][nf] = (f32x4){bv, bv, bv, bv};
    }
    const char* Pb = (const char*)Pl;
    for (int kt = 0; kt < 4; ++kt) {
        short8 a[2];
        #pragma unroll
        for (int mf = 0; mf < 2; ++mf)
            a[mf] = *(const short8*)(Pb + (m0 + mf * 16 + lr) * (PP * 2)
                                        + (kt * 32 + lg * 8) * 2);
        const short* wp = W2p + (((size_t)kt * 8 + (n0 >> 4)) * 64 + lane) * 8;
        #pragma unroll
        for (int nf = 0; nf < 4; ++nf) {
            short8 bf = *(const short8*)(wp + (size_t)nf * 64 * 8);
            #pragma unroll
            for (int mf = 0; mf < 2; ++mf)
                acc2[mf][nf] = __builtin_amdgcn_mfma_f32_16x16x32_bf16(
                    a[mf], bf, acc2[mf][nf], 0, 0, 0);
        }
    }

    #pragma unroll
    for (int mf = 0; mf < 2; ++mf)
        #pragma unroll
        for (int r = 0; r < 4; ++r) {
            int rl = m0 + mf * 16 + lg * 4 + r;
            float m = smk[rl] ? 1.f : 0.f;
            size_t ho = hrow(b, nn0 + rl);
            size_t hb = (size_t)(row0 + rl) * HID;
            #pragma unroll
            for (int nf = 0; nf < 4; ++nf) {
                int col = n0 + nf * 16 + lr;
                float hold = hout[ho + col];
                float hn = (hold + acc2[mf][nf][r]) * m;
                hout[ho + col] = hn;
                hbf_out[hb + col] = f2bf(hn);
            }
        }
}

extern "C" void kernel_launch(void* const* d_in, const int* in_sizes, int n_in,
                              void* d_out, int out_size, void* d_ws, size_t ws_size,
                              hipStream_t stream) {
    const float* nodes     = (const float*)d_in[0];
    const float* edge_feat = (const float*)d_in[1];
    const int*   edges     = (const int*)d_in[2];
    const int*   node_mask = (const int*)d_in[3];
    const int*   edge_mask = (const int*)d_in[4];
    const float* W_node    = (const float*)d_in[5];
    const float* W_edge    = (const float*)d_in[6];
    const float* marker    = (const float*)d_in[7];
    const float* eW1       = (const float*)d_in[8];
    const float* eb1       = (const float*)d_in[9];
    const float* eW2       = (const float*)d_in[10];
    const float* eb2       = (const float*)d_in[11];
    const float* nW1       = (const float*)d_in[12];
    const float* nb1       = (const float*)d_in[13];
    const float* nW2       = (const float*)d_in[14];
    const float* nb2       = (const float*)d_in[15];
    float* out = (float*)d_out;

    const size_t HN = (size_t)BB * NN * HID;        // 2,097,152
    char* wsb = (char*)d_ws;
    float*  agg    = (float*)wsb;   wsb += HN * 4;
    short*  hbf    = (short*)wsb;   wsb += HN * 2;
    float*  Wec    = (float*)wsb;   wsb += 3 * 16 * HID * 4;
    short*  W1p    = (short*)wsb;   wsb += 3 * 9 * 4096 * 2;
    short*  W2p    = (short*)wsb;   wsb += 3 * 4 * 4096 * 2;
    short*  nW1p   = (short*)wsb;   wsb += 3 * 8 * 4096 * 2;
    short*  nW2p   = (short*)wsb;   wsb += 3 * 4 * 4096 * 2;
    uint_t* cnt    = (uint_t*)wsb;  wsb += (size_t)BB * NN * 4;
    uint_t* cursor = (uint_t*)wsb;  wsb += (size_t)BB * NN * 4;
    uint_t* eidx   = (uint_t*)wsb;  wsb += (size_t)BB * EE * 4;
    if ((size_t)(wsb - (char*)d_ws) > ws_size) return;  // clean fail

    // ---- prolog (once per call) ----
    proj_nodes_kernel<<<(BB * NN) / 8, 128, 0, stream>>>(nodes, W_node, out, hbf);
    fuse_wec_kernel<<<48, 128, 0, stream>>>(W_edge, eW1, Wec);
    marker_kernel<<<1, 512, 0, stream>>>(marker, out);
    pack_e1_kernel<<<3 * 9 * 8, 64, 0, stream>>>(eW1, Wec, W1p);
    pack_w_kernel<<<3 * 4 * 8, 64, 0, stream>>>(eW2, W2p, 4, HID * HID);
    pack_w_kernel<<<3 * 8 * 8, 64, 0, stream>>>(nW1, nW1p, 8, 2 * HID * HID);
    pack_w_kernel<<<3 * 4 * 8, 64, 0, stream>>>(nW2, nW2p, 4, HID * HID);

    // counting sort of edges by (b, dst)
    hipMemsetAsync(cnt, 0, (size_t)BB * NN * 4, stream);
    hist_kernel<<<(BB * EE) / 256, 256, 0, stream>>>(edges, cnt);
    scan_kernel<<<1, 256, 0, stream>>>(cnt, cursor);
    scatter_kernel<<<(BB * EE) / 256, 256, 0, stream>>>(edges, cursor, eidx);

    for (int r = 0; r < NROUNDS; ++r) {
        hipMemsetAsync(agg, 0, HN * sizeof(float), stream);
        edge_mfma_csr_kernel<<<(BB * EE) / 64, 256, 0, stream>>>(
            hbf, edge_feat, edges, edge_mask, eidx,
            W1p + (size_t)r * 9 * 4096,
            W2p + (size_t)r * 4 * 4096,
            eb1 + r * HID,
            eb2 + r * HID,
            agg);
        node_mfma_kernel<<<(BB * NN) / 64, 256, 0, stream>>>(
            hbf, agg, node_mask,
            nW1p + (size_t)r * 8 * 4096,
            nW2p + (size_t)r * 4 * 4096,
            nb1 + r * HID,
            nb2 + r * HID,
            out, hbf);
    }
}